// Round 1
// 4854.169 us; speedup vs baseline: 1.2148x; 1.2148x over previous
//
#include <hip/hip_runtime.h>
#include <cstdint>
#include <cstddef>

typedef __bf16 bf16_t;
typedef __bf16 bf16x8 __attribute__((ext_vector_type(8)));
typedef float f32x4 __attribute__((ext_vector_type(4)));

#define LOG2E 1.4426950408889634f

// async global->LDS, 16B per lane. LDS dest = wave-uniform base + lane*16.
__device__ __forceinline__ void async16(const void* g, void* l) {
  __builtin_amdgcn_global_load_lds(
      (__attribute__((address_space(1))) unsigned int*)g,
      (__attribute__((address_space(3))) unsigned int*)l, 16, 0, 0);
}

// ---------------- cast kernels ----------------
__global__ void mha_cast_bf16(const float* __restrict__ s, bf16_t* __restrict__ d) {
  size_t i = (size_t)blockIdx.x * 256 + threadIdx.x;   // 8 elems per thread
  const float4* s4 = (const float4*)s;
  float4 a = s4[2 * i], b = s4[2 * i + 1];
  union { bf16_t h[8]; uint4 v; } u;
  u.h[0] = (bf16_t)a.x; u.h[1] = (bf16_t)a.y; u.h[2] = (bf16_t)a.z; u.h[3] = (bf16_t)a.w;
  u.h[4] = (bf16_t)b.x; u.h[5] = (bf16_t)b.y; u.h[6] = (bf16_t)b.z; u.h[7] = (bf16_t)b.w;
  ((uint4*)d)[i] = u.v;
}

// concat Wq|Wk|Wv -> bf16 [12288,4096]; each region is 2^24 elements
__global__ void mha_cast_cat3(const float* __restrict__ s0, const float* __restrict__ s1,
                              const float* __restrict__ s2, bf16_t* __restrict__ d) {
  size_t i = (size_t)blockIdx.x * 256 + threadIdx.x;
  size_t e = i * 8;
  int r = (int)(e >> 24);
  const float* s = (r == 0) ? s0 : ((r == 1) ? s1 : s2);
  size_t off = e & 0xFFFFFFull;
  const float4* s4 = (const float4*)(s + off);
  float4 a = s4[0], b = s4[1];
  union { bf16_t h[8]; uint4 v; } u;
  u.h[0] = (bf16_t)a.x; u.h[1] = (bf16_t)a.y; u.h[2] = (bf16_t)a.z; u.h[3] = (bf16_t)a.w;
  u.h[4] = (bf16_t)b.x; u.h[5] = (bf16_t)b.y; u.h[6] = (bf16_t)b.z; u.h[7] = (bf16_t)b.w;
  ((uint4*)d)[i] = u.v;
}

// ---------------- GEMM: C = A * B^T + bias (256x256 deep-pipelined) ----------------
// A: [M,K] bf16 row-major; B: [N,K] bf16 row-major (torch Linear weight)
// 256x256 tile, BK=64, 8 waves (2Mx4N), 512 threads, 16x16x32 MFMA.
// LDS: 2 buffers x (A 32KB + B 32KB) = 128 KiB. Chunk layout (16B chunks):
//   chunk c = k8*256 + m  -> conflict-free ds_read_b128, linear global_load_lds dest.
// Pipeline: depth-2 prefetch, inter-tile wait is vmcnt(8) (never 0 mid-loop).
__device__ __forceinline__ void stage8(const bf16_t* ga, const bf16_t* gb,
                                       bf16_t* la, bf16_t* lb) {
  // 4 issues per matrix: issue i covers chunks [i*512, i*512+512)
  async16(ga,      la);
  async16(ga + 16, la + 4096);
  async16(ga + 32, la + 8192);
  async16(ga + 48, la + 12288);
  async16(gb,      lb);
  async16(gb + 16, lb + 4096);
  async16(gb + 32, lb + 8192);
  async16(gb + 48, lb + 12288);
}

template <int OUTF32>
__global__ __launch_bounds__(512, 2) void mha_gemm_bt(
    const bf16_t* __restrict__ A, const bf16_t* __restrict__ B,
    const float* __restrict__ b0, const float* __restrict__ b1,
    const float* __restrict__ b2, void* __restrict__ Cp,
    int N, int K, int tilesN) {
  __shared__ bf16_t LDS[65536];  // 128 KiB
  const int tid = threadIdx.x;
  const int lane = tid & 63, w = tid >> 6;
  const int quad = lane >> 4, l16 = lane & 15;
  const int wr = w >> 2, wc = w & 3;

  // XCD-aware bijective swizzle (grids are multiples of 8)
  int wgid = blockIdx.x;
  const int nwg = gridDim.x;
  if ((nwg & 7) == 0) wgid = (wgid & 7) * (nwg >> 3) + (wgid >> 3);
  const int bm = wgid / tilesN, bn = wgid % tilesN;
  const int row0 = bm * 256, col0 = bn * 256;

  // staging: thread -> (row m, k-half khi); issue i loads k8 = 2i + khi
  const int ms = tid & 255, khi = tid >> 8;
  const bf16_t* gA = A + (size_t)(row0 + ms) * K + khi * 8;
  const bf16_t* gB = B + (size_t)(col0 + ms) * K + khi * 8;
  bf16_t* la = LDS + w * 512;           // buffer0 A staging base (wave-uniform)
  bf16_t* lb = LDS + 16384 + w * 512;   // buffer0 B staging base

  // fragment read bases (buffer0): chunk = (kk*4+quad)*256 + (wrow + 16*frag + l16)
  const bf16_t* ar = LDS + (quad * 256 + wr * 128 + l16) * 8;
  const bf16_t* br = LDS + (16384) + (quad * 256 + wc * 64 + l16) * 8;

  f32x4 acc[8][4] = {};

  const int NT = K >> 6;
  // prologue: stage tiles 0 (buf0) and 1 (buf1)
  stage8(gA, gB, la, lb);
  stage8(gA + 64, gB + 64, la + 32768, lb + 32768);
  asm volatile("s_waitcnt vmcnt(8)" ::: "memory");  // tile 0 landed
  __builtin_amdgcn_s_barrier();

  for (int t = 0; t < NT; ++t) {
    const int boff = (t & 1) << 15;  // 32768 elems per buffer
    const bf16_t* aptr = ar + boff;
    const bf16_t* bptr = br + boff;

    // ---- k-half 0: read frags, MFMA ----
    bf16x8 fa0[8], fb0[4];
#pragma unroll
    for (int i = 0; i < 8; ++i) fa0[i] = *(const bf16x8*)(aptr + i * 128);
#pragma unroll
    for (int u = 0; u < 4; ++u) fb0[u] = *(const bf16x8*)(bptr + u * 128);
#pragma unroll
    for (int i = 0; i < 8; ++i)
#pragma unroll
      for (int u = 0; u < 4; ++u)
        acc[i][u] = __builtin_amdgcn_mfma_f32_16x16x32_bf16(fa0[i], fb0[u], acc[i][u], 0, 0, 0);

    // ---- k-half 1: read frags (last reads of this buffer) ----
    bf16x8 fa1[8], fb1[4];
#pragma unroll
    for (int i = 0; i < 8; ++i) fa1[i] = *(const bf16x8*)(aptr + 8192 + i * 128);
#pragma unroll
    for (int u = 0; u < 4; ++u) fb1[u] = *(const bf16x8*)(bptr + 8192 + u * 128);

    asm volatile("s_waitcnt lgkmcnt(0)" ::: "memory");  // all my LDS reads of this buffer done
    __builtin_amdgcn_s_barrier();                       // ... and everyone else's

    // stage tile t+2 into the buffer we just finished reading
    if (t + 2 < NT)
      stage8(gA + (size_t)(t + 2) * 64, gB + (size_t)(t + 2) * 64, la + boff, lb + boff);

#pragma unroll
    for (int i = 0; i < 8; ++i)
#pragma unroll
      for (int u = 0; u < 4; ++u)
        acc[i][u] = __builtin_amdgcn_mfma_f32_16x16x32_bf16(fa1[i], fb1[u], acc[i][u], 0, 0, 0);

    __builtin_amdgcn_sched_barrier(0);  // keep MFMAs above the counted wait
    if (t + 1 < NT) {
      // wait for tile t+1's 8 loads only; keep t+2's 8 in flight (counted, never 0)
      if (t + 2 < NT) asm volatile("s_waitcnt vmcnt(8)" ::: "memory");
      else            asm volatile("s_waitcnt vmcnt(0)" ::: "memory");
      __builtin_amdgcn_s_barrier();
    }
  }

  // ---- epilogue: bias + store ----
#pragma unroll
  for (int u = 0; u < 4; ++u) {
    int col = col0 + wc * 64 + 16 * u + l16;
    int sel = col >> 12;
    const float* bb = (sel == 0) ? b0 : ((sel == 1) ? b1 : b2);
    float bias = bb[col & 4095];
#pragma unroll
    for (int i = 0; i < 8; ++i) {
#pragma unroll
      for (int r = 0; r < 4; ++r) {
        int row = row0 + wr * 128 + 16 * i + quad * 4 + r;
        float val = acc[i][u][r] + bias;
        if (OUTF32)
          ((float*)Cp)[(size_t)row * N + col] = val;
        else
          ((bf16_t*)Cp)[(size_t)row * N + col] = (bf16_t)val;
      }
    }
  }
}

// ---------------- fused causal flash attention ----------------
// qkv: [B*L, 12288] bf16 (Q|K|V per row, each [H=32][HD=128])
// out: [B*L, 4096] bf16 (b,l,h,hd layout == A matrix of output projection)
// block = (b, h, q-tile of 128). 4 waves; wave w owns q rows [w*32, w*32+32).
// K-tile = 64 keys. LDS 48KB: Ks 16KB + R2 32KB (Q staging, then Vts 16KB + Ps 16KB).
__global__ __launch_bounds__(256, 2) void mha_attn(const bf16_t* __restrict__ qkv,
                                                   bf16_t* __restrict__ out) {
  __shared__ bf16_t Ks[64 * 128];
  __shared__ bf16_t R2[128 * 128];
  const int tid = threadIdx.x;
  const int lane = tid & 63, w = tid >> 6;
  const int quad = lane >> 4, l16 = lane & 15;
  const int qt = blockIdx.x & 3;
  const int h = (blockIdx.x >> 2) & 31;
  const int b = blockIdx.x >> 7;
  const float scale = 0.08838834764831845f;  // 1/sqrt(128)
  const size_t rs = 12288;

  // ---- stage Q tile [128 q][128 hd], chunk c = hd8*128 + m ----
  const bf16_t* baseQ = qkv + (size_t)(b * 512 + qt * 128) * rs + h * 128;
#pragma unroll
  for (int i = 0; i < 8; ++i) {
    int c = i * 256 + tid;
    int hd8 = c >> 7, m = c & 127;
    async16(baseQ + (size_t)m * rs + hd8 * 8, R2 + (i * 256 + w * 64) * 8);
  }
  __syncthreads();
  bf16x8 qf[2][4];
#pragma unroll
  for (int t = 0; t < 2; ++t)
#pragma unroll
    for (int kk = 0; kk < 4; ++kk)
      qf[t][kk] = *(const bf16x8*)(R2 + ((kk * 4 + quad) * 128 + w * 32 + 16 * t + l16) * 8);

  f32x4 O[2][8] = {};
  float mrow[2][4], lrow[2][4];
#pragma unroll
  for (int t = 0; t < 2; ++t)
#pragma unroll
    for (int r = 0; r < 4; ++r) { mrow[t][r] = -1e30f; lrow[t][r] = 0.f; }

  bf16_t* Vts = R2;                       // [d 128][key 64], chunk c = key8*128 + d
  bf16_t* Ps = R2 + 8192 + w * 2048;      // wave-private [q 32][key 64], chunk c = key8*32 + q

  const int ktEnd = 2 * qt + 1;
  for (int kt = 0; kt <= ktEnd; ++kt) {
    __syncthreads();  // all waves done with Ks/Vts (and Q region, first iter)
    // stage K tile [64 key][128 hd], chunk c = hd8*64 + key
    const bf16_t* baseK = qkv + (size_t)(b * 512 + kt * 64) * rs + 4096 + h * 128;
#pragma unroll
    for (int i = 0; i < 4; ++i) {
      int c = i * 256 + tid;
      int hd8 = c >> 6, key = c & 63;
      async16(baseK + (size_t)key * rs + hd8 * 8, Ks + (i * 256 + w * 64) * 8);
    }
    // stage V transposed into Vts (manual; rotated write order -> ~4-way conflicts)
    const bf16_t* baseV = qkv + (size_t)(b * 512 + kt * 64) * rs + 8192 + h * 128;
#pragma unroll
    for (int j = 0; j < 4; ++j) {
      int idx = j * 256 + tid;
      int d8 = idx & 15, key = idx >> 4;
      bf16x8 vv = *(const bf16x8*)(baseV + (size_t)key * rs + d8 * 8);
#pragma unroll
      for (int e = 0; e < 8; ++e) {
        int ee = (e + d8) & 7;
        int d = d8 * 8 + ee;
        Vts[((key >> 3) * 128 + d) * 8 + (key & 7)] = vv[ee];
      }
    }
    __syncthreads();

    // ---- S = Q K^T ----
    f32x4 S[2][4] = {};
#pragma unroll
    for (int kk = 0; kk < 4; ++kk) {
      bf16x8 kf[4];
#pragma unroll
      for (int u = 0; u < 4; ++u)
        kf[u] = *(const bf16x8*)(Ks + ((kk * 4 + quad) * 64 + 16 * u + l16) * 8);
#pragma unroll
      for (int t = 0; t < 2; ++t)
#pragma unroll
        for (int u = 0; u < 4; ++u)
          S[t][u] = __builtin_amdgcn_mfma_f32_16x16x32_bf16(qf[t][kk], kf[u], S[t][u], 0, 0, 0);
    }

    // ---- scale + causal mask ----
    const bool maskTile = (kt >= 2 * qt);
#pragma unroll
    for (int t = 0; t < 2; ++t) {
      int qbase = qt * 128 + w * 32 + 16 * t + quad * 4;
#pragma unroll
      for (int u = 0; u < 4; ++u) {
        int key = kt * 64 + 16 * u + l16;
#pragma unroll
        for (int r = 0; r < 4; ++r) {
          float v = S[t][u][r] * scale;
          if (maskTile && key > qbase + r) v = -1e30f;
          S[t][u][r] = v;
        }
      }
    }

    // ---- online softmax (rows live across 16 lanes of each quad) ----
#pragma unroll
    for (int t = 0; t < 2; ++t) {
#pragma unroll
      for (int r = 0; r < 4; ++r) {
        float mx = fmaxf(fmaxf(S[t][0][r], S[t][1][r]), fmaxf(S[t][2][r], S[t][3][r]));
        mx = fmaxf(mx, __shfl_xor(mx, 1));
        mx = fmaxf(mx, __shfl_xor(mx, 2));
        mx = fmaxf(mx, __shfl_xor(mx, 4));
        mx = fmaxf(mx, __shfl_xor(mx, 8));
        float mnew = fmaxf(mrow[t][r], mx);
        float alpha = exp2f((mrow[t][r] - mnew) * LOG2E);
        mrow[t][r] = mnew;
        float psum = 0.f;
#pragma unroll
        for (int u = 0; u < 4; ++u) {
          float p = exp2f((S[t][u][r] - mnew) * LOG2E);
          S[t][u][r] = p;
          psum += p;
        }
        psum += __shfl_xor(psum, 1);
        psum += __shfl_xor(psum, 2);
        psum += __shfl_xor(psum, 4);
        psum += __shfl_xor(psum, 8);
        lrow[t][r] = lrow[t][r] * alpha + psum;
#pragma unroll
        for (int u = 0; u < 8; ++u) O[t][u][r] *= alpha;
      }
    }

    // ---- write P to wave-private LDS (C-layout -> chunked A-layout) ----
#pragma unroll
    for (int t = 0; t < 2; ++t)
#pragma unroll
      for (int u = 0; u < 4; ++u) {
        int key = 16 * u + l16;
#pragma unroll
        for (int rr = 0; rr < 4; ++rr) {
          int r = (rr + quad) & 3;  // rotation: spread banks
          Ps[((key >> 3) * 32 + 16 * t + quad * 4 + r) * 8 + (key & 7)] = (bf16_t)S[t][u][r];
        }
      }

    // ---- O += P V  (A = P from Ps, B = V^T from Vts; wave-local, no barrier) ----
#pragma unroll
    for (int kk = 0; kk < 2; ++kk) {
      bf16x8 pf[2], vf[8];
#pragma unroll
      for (int t = 0; t < 2; ++t)
        pf[t] = *(const bf16x8*)(Ps + ((kk * 4 + quad) * 32 + 16 * t + l16) * 8);
#pragma unroll
      for (int u = 0; u < 8; ++u)
        vf[u] = *(const bf16x8*)(Vts + ((kk * 4 + quad) * 128 + 16 * u + l16) * 8);
#pragma unroll
      for (int t = 0; t < 2; ++t)
#pragma unroll
        for (int u = 0; u < 8; ++u)
          O[t][u] = __builtin_amdgcn_mfma_f32_16x16x32_bf16(pf[t], vf[u], O[t][u], 0, 0, 0);
    }
  }

  // ---- epilogue: normalize and write [b,l,h,hd] bf16 ----
  bf16_t* outBase = out + (size_t)(b * 512 + qt * 128) * 4096 + h * 128;
#pragma unroll
  for (int t = 0; t < 2; ++t)
#pragma unroll
    for (int u = 0; u < 8; ++u) {
      int d = 16 * u + l16;
#pragma unroll
      for (int r = 0; r < 4; ++r) {
        int q = w * 32 + 16 * t + quad * 4 + r;
        float val = O[t][u][r] / lrow[t][r];
        outBase[(size_t)q * 4096 + d] = (bf16_t)val;
      }
    }
}

// ---------------- launch ----------------
extern "C" void kernel_launch(void* const* d_in, const int* in_sizes, int n_in,
                              void* d_out, int out_size, void* d_ws, size_t ws_size,
                              hipStream_t stream) {
  const float* x  = (const float*)d_in[0];
  const float* Wq = (const float*)d_in[1];
  const float* bq = (const float*)d_in[2];
  const float* Wk = (const float*)d_in[3];
  const float* bk = (const float*)d_in[4];
  const float* Wv = (const float*)d_in[5];
  const float* bv = (const float*)d_in[6];
  const float* Wo = (const float*)d_in[7];
  const float* bo = (const float*)d_in[8];

  char* ws = (char*)d_ws;
  // layout (640 MiB total):
  //  [0, 128MiB)      x_bf16, later reused as attention output (A of out-proj)
  //  [128, 224MiB)    Wqkv bf16 [12288,4096]
  //  [224, 256MiB)    Wo bf16 [4096,4096]
  //  [256, 640MiB)    qkv bf16 [16384, 12288]
  bf16_t* xb   = (bf16_t*)ws;
  bf16_t* wqkv = (bf16_t*)(ws + 134217728ull);
  bf16_t* wob  = (bf16_t*)(ws + 134217728ull + 100663296ull);
  bf16_t* qkvb = (bf16_t*)(ws + 134217728ull + 100663296ull + 33554432ull);

  // casts
  mha_cast_bf16<<<32768, 256, 0, stream>>>(x, xb);          // 2^26 elems
  mha_cast_cat3<<<24576, 256, 0, stream>>>(Wq, Wk, Wv, wqkv);
  mha_cast_bf16<<<8192, 256, 0, stream>>>(Wo, wob);         // 2^24 elems

  // QKV projection: [16384,4096] x [12288,4096]^T -> [16384,12288]
  // 64 x 48 = 3072 tiles of 256x256
  mha_gemm_bt<0><<<3072, 512, 0, stream>>>(xb, wqkv, bq, bk, bv, qkvb, 12288, 4096, 48);

  // fused causal attention -> xb as [16384,4096] bf16
  mha_attn<<<4096, 256, 0, stream>>>(qkvb, xb);

  // output projection: [16384,4096] x [4096,4096]^T + bo -> d_out fp32
  // 64 x 16 = 1024 tiles of 256x256
  mha_gemm_bt<1><<<1024, 512, 0, stream>>>(xb, wob, bo, bo, bo, d_out, 4096, 4096, 16);
}